// Round 2
// 297.759 us; speedup vs baseline: 1.0267x; 1.0267x over previous
//
#include <hip/hip_runtime.h>

// LSTMP via MFMA, fp32 I/O, f16 compute, fp32 accumulate.
// B=4096, T=512, IN=4, HID=64, PROJ=52. Grid 256 x 512thr (8 waves, 2/SIMD),
// 16 batch/block.
//
// Round-13 = Round-12 arithmetic + GATE-PACKED TILES, 2 WAVES/SIMD:
// each wave owns an 8-hid block and packs TWO gates per 16x16 MFMA tile with
// ROW INTERLEAVING:  P0 rows = [i(h),f(h)] interleaved, P1 rows = [g(h),o(h)].
// A lane's f32x4 accumulator then holds (i,f) resp (g,o) of the SAME two hid
// cells -> activations need NO cross-lane exchange, all 64 lanes active,
// 2 cells/lane (20 trans/wave/step vs 40). Per-SIMD totals conserved
// (12 MFMA, 40 trans) but two co-resident waves now fill each other's
// stall cycles (ds_read latency, MFMA latency, trans chains, barrier skew).
// Row interleave is a pure permutation of independent MFMA rows: per-gate
// accumulate order (xb seed, M0, M1) and all rounding identical to R12
// -> absmax exactly 9.765625e-4.
//   gates = (Whh@Whr)@d + [Wih|b]@[x;1]   (M precomputed per block, fp32)
// x staged to LDS as f16 once; d double-buffered in LDS (136B rows);
// ONE lgkm-only barrier/step; h only in epilogue (Whr@d_T, waves 0-3).
// log2e folded (i,f,o rows xL; g rows x2L; c' = 2L*c). RTNE f16 d.
//
// (Round-14 resubmit: R13 bench was an infra failure — container acquisition
// failed twice, no kernel signal. Source identical to R13.)

#define T_STEPS 512
#define HID 64
#define NPROJ 52
#define NBATCH 16
#define ROWB 136
#define DBYTES (NBATCH * ROWB)     // 2176 B per d buffer
#define XBYTES (T_STEPS * 128)     // 65536 B: x_lds[t][b] 8B cells (4 x f16)
#define LOG2E 1.44269504088896340736f

typedef _Float16 half8 __attribute__((ext_vector_type(8)));
typedef float f32x4 __attribute__((ext_vector_type(4)));

__device__ __forceinline__ float exp2_f(float x) {
#if __has_builtin(__builtin_amdgcn_exp2f)
    return __builtin_amdgcn_exp2f(x);
#else
    return exp2f(x);
#endif
}
__device__ __forceinline__ float rcp_f(float x) {
    return __builtin_amdgcn_rcpf(x);
}

__global__ __launch_bounds__(512, 2)
void lstmp_kernel(const float* __restrict__ x,      // [4096][512][4]
                  const float* __restrict__ Wih,    // [256][4]
                  const float* __restrict__ Whh,    // [256][52]
                  const float* __restrict__ bih,    // [256]
                  const float* __restrict__ bhh,    // [256]
                  const float* __restrict__ Whr,    // [52][64]
                  float* __restrict__ out)          // [4096][52]
{
    __shared__ char lds[XBYTES + 2 * DBYTES];
    char* xl = lds;                 // x_lds: [t][b] 8B cells
    char* dl = lds + XBYTES;        // double-buffered d, [16 batch][136B]

    const int tid  = threadIdx.x;
    const int lane = tid & 63;
    const int wave = tid >> 6;           // 0..7, owns hid block [8w, 8w+8)
    const int quad = lane >> 4;
    const int col  = lane & 15;          // batch (B/C col), tile row (A)

    // ---- zero d buffers (t=0 reads buffer 0 as d(-1)=0) ----
    {
        unsigned* p = (unsigned*)dl;
        for (int i = tid; i < (int)(2 * DBYTES / 4); i += 512) p[i] = 0u;
    }

    // ---- stage x -> LDS as f16 (one-time; coalesced global reads) ----
    {
        const float4* xg = (const float4*)x + (size_t)blockIdx.x * NBATCH * T_STEPS;
        for (int i = tid; i < NBATCH * T_STEPS; i += 512) {
            const int b = i >> 9;          // global layout is b-major
            const int t = i & (T_STEPS - 1);
            const float4 v = xg[i];
            union { _Float16 h[4]; unsigned long long q; } u;
            u.h[0] = (_Float16)v.x; u.h[1] = (_Float16)v.y;
            u.h[2] = (_Float16)v.z; u.h[3] = (_Float16)v.w;
            *(unsigned long long*)(xl + t * 128 + b * 8) = u.q;
        }
    }

    // ---- this lane's two A-frag rows (tile row = col, interleaved packing) ----
    // tile row tr of P0 -> gate (tr&1 ? f : i), hid = 8*wave + (tr>>1)
    // tile row tr of P1 -> gate (tr&1 ? o : g), hid = 8*wave + (tr>>1)
    const int hw    = wave * 8 + (col >> 1);
    const int gsel  = col & 1;
    const int rowP0 = gsel * HID + hw;          // gate 0 (i) / 1 (f)
    const int rowP1 = (2 + gsel) * HID + hw;    // gate 2 (g) / 3 (o)

    // ---- one-time: M = Whh @ Whr for the two packed rows (fp32) ----
    float macc[2][16];
#pragma unroll
    for (int g = 0; g < 2; ++g)
#pragma unroll
        for (int kk = 0; kk < 16; ++kk) macc[g][kk] = 0.0f;

    for (int p = 0; p < NPROJ; ++p) {
        const float w0 = Whh[rowP0 * NPROJ + p];
        const float w1 = Whh[rowP1 * NPROJ + p];
        const float* wr = Whr + p * HID + quad * 8;
        const float4 r0 = *(const float4*)(wr);
        const float4 r1 = *(const float4*)(wr + 4);
        const float4 r2 = *(const float4*)(wr + 32);
        const float4 r3 = *(const float4*)(wr + 36);
        const float rk[16] = {r0.x, r0.y, r0.z, r0.w, r1.x, r1.y, r1.z, r1.w,
                              r2.x, r2.y, r2.z, r2.w, r3.x, r3.y, r3.z, r3.w};
#pragma unroll
        for (int kk = 0; kk < 16; ++kk) {
            macc[0][kk] = fmaf(w0, rk[kk], macc[0][kk]);
            macc[1][kk] = fmaf(w1, rk[kk], macc[1][kk]);
        }
    }

    // ---- fold log2e, convert to f16 A-frags ----
    const float s0 = LOG2E;                                  // i and f rows
    const float s1 = (gsel == 0) ? (2.0f * LOG2E) : LOG2E;   // g rows x2L, o rows xL
    half8 aM0[2], aM1[2];   // M-part, K=64 (2 chunks)
    half8 aXB0, aXB1;       // [Wih | bias] part, K=32 (quad0: k<4 = x, k==4 = 1-col)
#pragma unroll
    for (int ch = 0; ch < 2; ++ch)
#pragma unroll
        for (int j = 0; j < 8; ++j) {
            aM0[ch][j] = (_Float16)(macc[0][ch * 8 + j] * s0);
            aM1[ch][j] = (_Float16)(macc[1][ch * 8 + j] * s1);
        }
#pragma unroll
    for (int j = 0; j < 8; ++j) {
        const int k = quad * 8 + j;
        float v0 = 0.0f, v1 = 0.0f;
        if (k < 4) {
            v0 = Wih[rowP0 * 4 + k];
            v1 = Wih[rowP1 * 4 + k];
        } else if (k == 4) {
            v0 = bih[rowP0] + bhh[rowP0];
            v1 = bih[rowP1] + bhh[rowP1];
        }
        aXB0[j] = (_Float16)(v0 * s0);
        aXB1[j] = (_Float16)(v1 * s1);
    }

    float cacc[2] = {0.0f, 0.0f};        // c' = 2L*c; cells hid = 8w+2q+{0,1}

    const int dwoff  = col * ROWB + wave * 16 + quad * 4;  // d write (b32, 2 f16)
    const int drbase = col * ROWB + quad * 16;             // d read base (+ch*64)
    const char* xrd  = xl + col * 8;                       // + t*128 per step

    __syncthreads();   // staging + zeros visible

    // ---- pre-seed accumulators with xb contribution for t=0 ----
    f32x4 a0, a1;
    {
        half8 bx;
#pragma unroll
        for (int j = 0; j < 8; ++j) bx[j] = (_Float16)0.0f;
        if (quad == 0) {
            union { unsigned long long q; _Float16 h[4]; } u;
            u.q = *(const unsigned long long*)(xrd + 0 * 128);
            bx[0] = u.h[0]; bx[1] = u.h[1]; bx[2] = u.h[2]; bx[3] = u.h[3];
            bx[4] = (_Float16)1.0f;
        }
        const f32x4 z = {0.f, 0.f, 0.f, 0.f};
        a0 = __builtin_amdgcn_mfma_f32_16x16x32_f16(aXB0, bx, z, 0, 0, 0);
        a1 = __builtin_amdgcn_mfma_f32_16x16x32_f16(aXB1, bx, z, 0, 0, 0);
    }

#pragma unroll 1
    for (int t = 0; t < T_STEPS; ++t) {
        const char* rbuf = dl + (t & 1) * DBYTES;
        char* wbuf = dl + ((t + 1) & 1) * DBYTES;

        // ---- post-barrier critical path: d(t-1) B-frags, then 4 M-MFMA ----
        half8 bd0, bd1;
        {
            const char* p0 = rbuf + drbase;
            union { unsigned long long q[2]; half8 h; } u0, u1;
            u0.q[0] = *(const unsigned long long*)(p0);
            u0.q[1] = *(const unsigned long long*)(p0 + 8);
            u1.q[0] = *(const unsigned long long*)(p0 + 64);
            u1.q[1] = *(const unsigned long long*)(p0 + 72);
            bd0 = u0.h; bd1 = u1.h;
        }
        a0 = __builtin_amdgcn_mfma_f32_16x16x32_f16(aM0[0], bd0, a0, 0, 0, 0);
        a1 = __builtin_amdgcn_mfma_f32_16x16x32_f16(aM1[0], bd0, a1, 0, 0, 0);
        a0 = __builtin_amdgcn_mfma_f32_16x16x32_f16(aM0[1], bd1, a0, 0, 0, 0);
        a1 = __builtin_amdgcn_mfma_f32_16x16x32_f16(aM1[1], bd1, a1, 0, 0, 0);

        // ---- activations + cell update: 2 cells/lane, no cross-lane ----
        // a0 = [i(c0), f(c0), i(c1), f(c1)], a1 = [g(c0), o(c0), g(c1), o(c1)]
        // cell u: hid = 8*wave + 2*quad + u, batch = col
        union { _Float16 h[2]; unsigned w; } du;
#pragma unroll
        for (int u = 0; u < 2; ++u) {
            const float iv = rcp_f(1.0f + exp2_f(-a0[2 * u]));                    // sigmoid
            const float fv = rcp_f(1.0f + exp2_f(-a0[2 * u + 1]));
            const float ov = rcp_f(1.0f + exp2_f(-a1[2 * u + 1]));
            const float gs = fmaf(-4.0f * LOG2E, rcp_f(1.0f + exp2_f(a1[2 * u])),
                                  2.0f * LOG2E);                                  // 2L*tanh(g)
            const float cn = fmaf(fv, cacc[u], iv * gs);                          // c' = 2L*c
            cacc[u] = cn;
            const float th = fmaf(-2.0f, rcp_f(1.0f + exp2_f(cn)), 1.0f);         // tanh(c)
            du.h[u] = (_Float16)(ov * th);                                        // RTNE
        }
        *(unsigned*)(wbuf + dwoff) = du.w;

        // ---- pre-barrier: xb-MFMA for step t+1 (independent of d(t)) ----
        {
            const int tn = (t + 1 < T_STEPS) ? (t + 1) : (T_STEPS - 1);
            half8 bx;
#pragma unroll
            for (int j = 0; j < 8; ++j) bx[j] = (_Float16)0.0f;
            if (quad == 0) {
                union { unsigned long long q; _Float16 h[4]; } u;
                u.q = *(const unsigned long long*)(xrd + tn * 128);
                bx[0] = u.h[0]; bx[1] = u.h[1]; bx[2] = u.h[2]; bx[3] = u.h[3];
                bx[4] = (_Float16)1.0f;
            }
            const f32x4 z = {0.f, 0.f, 0.f, 0.f};
            a0 = __builtin_amdgcn_mfma_f32_16x16x32_f16(aXB0, bx, z, 0, 0, 0);
            a1 = __builtin_amdgcn_mfma_f32_16x16x32_f16(aXB1, bx, z, 0, 0, 0);
        }

        __syncthreads();   // the ONLY barrier per step (lgkm-only drain)
    }

    // ---- epilogue: h_T = Whr @ d(511); d(511) is in buffer 0; waves 0-3 ----
    if (wave < 4) {
        half8 aP[2];
        const int prow = wave * 16 + col;
#pragma unroll
        for (int ch = 0; ch < 2; ++ch)
#pragma unroll
            for (int j = 0; j < 8; ++j) {
                const int k = ch * 32 + quad * 8 + j;
                aP[ch][j] = (_Float16)((prow < NPROJ) ? Whr[prow * HID + k] : 0.0f);
            }

        half8 bd0, bd1;
        {
            const char* p0 = dl + 0 * DBYTES + drbase;
            union { unsigned long long q[2]; half8 h; } u0, u1;
            u0.q[0] = *(const unsigned long long*)(p0);
            u0.q[1] = *(const unsigned long long*)(p0 + 8);
            u1.q[0] = *(const unsigned long long*)(p0 + 64);
            u1.q[1] = *(const unsigned long long*)(p0 + 72);
            bd0 = u0.h; bd1 = u1.h;
        }
        f32x4 hf = {0.f, 0.f, 0.f, 0.f};
        hf = __builtin_amdgcn_mfma_f32_16x16x32_f16(aP[0], bd0, hf, 0, 0, 0);
        hf = __builtin_amdgcn_mfma_f32_16x16x32_f16(aP[1], bd1, hf, 0, 0, 0);

        // store: p = wave*16 + quad*4 + r, batch = col  (wave 3: only quad 0 valid)
        const size_t bg = (size_t)blockIdx.x * NBATCH + col;
        float* o = out + bg * NPROJ;
        const int p0 = wave * 16 + quad * 4;
#pragma unroll
        for (int r = 0; r < 4; ++r) {
            const int p = p0 + r;
            if (p < NPROJ) o[p] = hf[r];
        }
    }
}

extern "C" void kernel_launch(void* const* d_in, const int* in_sizes, int n_in,
                              void* d_out, int out_size, void* d_ws, size_t ws_size,
                              hipStream_t stream) {
    const float* x   = (const float*)d_in[0];
    const float* Wih = (const float*)d_in[1];
    const float* Whh = (const float*)d_in[2];
    const float* bih = (const float*)d_in[3];
    const float* bhh = (const float*)d_in[4];
    const float* Whr = (const float*)d_in[5];
    float* out = (float*)d_out;

    dim3 grid(4096 / NBATCH);   // 256 blocks, 1 per CU
    dim3 block(512);            // 8 waves, 2 waves/SIMD
    lstmp_kernel<<<grid, block, 0, stream>>>(x, Wih, Whh, bih, bhh, Whr, out);
}